// Round 1
// baseline (2820.577 us; speedup 1.0000x reference)
//
#include <hip/hip_runtime.h>
#include <hip/hip_bf16.h>

#define BATCH 16
#define CDIM 128
#define HDIM 32
#define WDIM 32
#define NCODES 8192
#define NTOT (BATCH*CDIM*HDIM*WDIM)   // 2097152
#define TR 16                          // rows per argmin block

// ---------------- init: z_rest = z_enc, z_dec = 0 ----------------
__global__ void init_kernel(const float* __restrict__ ze,
                            float* __restrict__ zrest,
                            float* __restrict__ zdec) {
    int i = blockIdx.x * 256 + threadIdx.x;
    zrest[i] = ze[i];
    zdec[i]  = 0.0f;
}

// ---------------- e_sq[v] = sum_c emb[v][c]^2 ----------------
__global__ void esq_kernel(const float* __restrict__ emb,
                           float* __restrict__ esq) {
    int v    = blockIdx.x * 4 + (threadIdx.x >> 6);
    int lane = threadIdx.x & 63;
    float2 e = *(const float2*)(emb + (size_t)v * CDIM + lane * 2);
    float s = e.x * e.x + e.y * e.y;
    #pragma unroll
    for (int d = 32; d; d >>= 1) s += __shfl_xor(s, d, 64);
    if (lane == 0) esq[v] = s;
}

// ---------------- area downsample: zd[row][c], row=(b,ph,pw) ----------------
__global__ void down_kernel(const float* __restrict__ zr,
                            float* __restrict__ zd,
                            int pn, int f) {
    int row = blockIdx.x;
    int c   = threadIdx.x;
    int pp  = pn * pn;
    int b   = row / pp;
    int rem = row - b * pp;
    int ph  = rem / pn;
    int pw  = rem - ph * pn;
    const float* src = zr + (((size_t)b * CDIM + c) * HDIM + ph * f) * WDIM + pw * f;
    float s = 0.0f;
    for (int u = 0; u < f; u++)
        for (int v = 0; v < f; v++)
            s += src[u * WDIM + v];
    zd[(size_t)row * CDIM + c] = s * (1.0f / (f * f));
}

// ---------------- argmin over codes: token[row] ----------------
// Block: 256 threads, TR=16 rows staged in LDS.
// Each thread processes 2 codes at a time (v0, v0+1), 16 passes of 512 codes.
__global__ __launch_bounds__(256) void argmin_kernel(
        const float* __restrict__ zd,
        const float* __restrict__ emb,
        const float* __restrict__ esq,
        int* __restrict__ token) {
    __shared__ float rowsm[TR][CDIM];
    __shared__ unsigned long long wbuf[4][TR];

    int row0 = blockIdx.x * TR;
    int tid  = threadIdx.x;

    for (int idx = tid; idx < TR * CDIM; idx += 256) {
        int r = idx >> 7, k = idx & 127;
        rowsm[r][k] = zd[(size_t)(row0 + r) * CDIM + k];
    }
    __syncthreads();

    float best[TR];
    int   bidx[TR];
    #pragma unroll
    for (int r = 0; r < TR; r++) { best[r] = 1e30f; bidx[r] = 0; }

    for (int j = 0; j < NCODES / 512; j++) {
        int v0 = 2 * tid + 512 * j;
        float acc0[TR], acc1[TR];
        #pragma unroll
        for (int r = 0; r < TR; r++) { acc0[r] = 0.0f; acc1[r] = 0.0f; }
        const float4* e0 = (const float4*)(emb + (size_t)v0 * CDIM);
        const float4* e1 = (const float4*)(emb + (size_t)(v0 + 1) * CDIM);
        #pragma unroll 4
        for (int k4 = 0; k4 < CDIM / 4; k4++) {
            float4 a = e0[k4];
            float4 bb = e1[k4];
            #pragma unroll
            for (int r = 0; r < TR; r++) {
                float4 rv = *(const float4*)&rowsm[r][k4 * 4];
                acc0[r] += a.x * rv.x + a.y * rv.y + a.z * rv.z + a.w * rv.w;
                acc1[r] += bb.x * rv.x + bb.y * rv.y + bb.z * rv.z + bb.w * rv.w;
            }
        }
        float es0 = esq[v0], es1 = esq[v0 + 1];
        #pragma unroll
        for (int r = 0; r < TR; r++) {
            float s0 = es0 - 2.0f * acc0[r];
            if (s0 < best[r]) { best[r] = s0; bidx[r] = v0; }
            float s1 = es1 - 2.0f * acc1[r];
            if (s1 < best[r]) { best[r] = s1; bidx[r] = v0 + 1; }
        }
    }

    int lane = tid & 63, wv = tid >> 6;
    #pragma unroll
    for (int r = 0; r < TR; r++) {
        unsigned int fb = __float_as_uint(best[r]);
        fb = (fb & 0x80000000u) ? ~fb : (fb | 0x80000000u);
        unsigned long long key =
            ((unsigned long long)fb << 32) | (unsigned int)bidx[r];
        #pragma unroll
        for (int d = 32; d; d >>= 1) {
            unsigned long long o = __shfl_xor(key, d, 64);
            key = (o < key) ? o : key;
        }
        if (lane == 0) wbuf[wv][r] = key;
    }
    __syncthreads();
    if (tid < TR) {
        unsigned long long k0 = wbuf[0][tid];
        #pragma unroll
        for (int w2 = 1; w2 < 4; w2++) {
            unsigned long long o = wbuf[w2][tid];
            k0 = (o < k0) ? o : k0;
        }
        token[row0 + tid] = (int)(k0 & 0xFFFFFFFFu);
    }
}

// ---------------- bicubic weight (a = -0.75), t = |arg| <= 2 ----------------
__device__ __forceinline__ float cubicw(float t) {
    float t2 = t * t;
    if (t <= 1.0f) return (1.25f * t - 2.25f) * t2 + 1.0f;
    return -0.75f * (((t - 5.0f) * t + 8.0f) * t - 4.0f);
}

// ---------------- upsample + residual update + output ----------------
__global__ __launch_bounds__(256) void up_kernel(
        const float* __restrict__ emb,
        const int* __restrict__ token,
        float* __restrict__ zdec,
        float* __restrict__ zrest,
        float* __restrict__ out,
        int pn, int last) {
    __shared__ float wtab[32][5];
    __shared__ int   itab[32][5];
    int tid = threadIdx.x;
    if (!last && tid < 128) {
        int pos = tid >> 2, tap = tid & 3;
        float s  = (float)pn * (1.0f / 32.0f);
        float x  = ((float)pos + 0.5f) * s - 0.5f;
        float x0 = floorf(x);
        float t  = x - x0;
        int   off = tap - 1;
        float w  = cubicw(fabsf((float)off - t));
        int   jj = (int)x0 + off;
        jj = min(max(jj, 0), pn - 1);
        wtab[pos][tap] = w;
        itab[pos][tap] = jj;
    }
    __syncthreads();

    int i  = blockIdx.x * 256 + tid;
    int w_ = i & 31;
    int h  = (i >> 5) & 31;
    int c  = (i >> 10) & 127;
    int b  = i >> 17;

    float zu;
    if (last) {
        int tok = token[(b << 10) + (h << 5) + w_];
        zu = emb[(size_t)tok * CDIM + c];
    } else {
        int base = b * pn * pn;
        zu = 0.0f;
        #pragma unroll
        for (int u = 0; u < 4; u++) {
            float whu = wtab[h][u];
            int   ih  = itab[h][u] * pn;
            float acc = 0.0f;
            #pragma unroll
            for (int v = 0; v < 4; v++) {
                int tok = token[base + ih + itab[w_][v]];
                acc += wtab[w_][v] * emb[(size_t)tok * CDIM + c];
            }
            zu += whu * acc;
        }
    }
    float nd = zdec[i] + zu;
    zdec[i]  = nd;
    zrest[i] = zrest[i] - zu;
    out[i]   = nd;
}

extern "C" void kernel_launch(void* const* d_in, const int* in_sizes, int n_in,
                              void* d_out, int out_size, void* d_ws, size_t ws_size,
                              hipStream_t stream) {
    const float* z_enc = (const float*)d_in[0];
    const float* emb   = (const float*)d_in[1];
    float* out = (float*)d_out;
    float* ws  = (float*)d_ws;

    float* zrest = ws;
    float* zdec  = ws + NTOT;
    float* zd    = ws + 2 * (size_t)NTOT;
    float* esq   = ws + 3 * (size_t)NTOT;
    int*   token = (int*)(ws + 3 * (size_t)NTOT + NCODES);

    init_kernel<<<NTOT / 256, 256, 0, stream>>>(z_enc, zrest, zdec);
    esq_kernel<<<NCODES / 4, 256, 0, stream>>>(emb, esq);

    const int MS_[6] = {1, 2, 4, 8, 16, 32};
    for (int lvl = 0; lvl < 6; lvl++) {
        int pn   = MS_[lvl];
        int last = (lvl == 5) ? 1 : 0;
        int rows = BATCH * pn * pn;
        down_kernel<<<rows, CDIM, 0, stream>>>(zrest, zd, pn, HDIM / pn);
        argmin_kernel<<<rows / TR, 256, 0, stream>>>(zd, emb, esq, token);
        up_kernel<<<NTOT / 256, 256, 0, stream>>>(emb, token, zdec, zrest,
                                                  out + (size_t)lvl * NTOT, pn, last);
    }
}

// Round 2
// 712.863 us; speedup vs baseline: 3.9567x; 3.9567x over previous
//
#include <hip/hip_runtime.h>
#include <hip/hip_bf16.h>

#define BATCH 16
#define CDIM 128
#define HDIM 32
#define WDIM 32
#define NCODES 8192
#define NTOT (BATCH*CDIM*HDIM*WDIM)   // 2097152
#define MAXROWS 16384                  // rows at last level (padded pool)

typedef __attribute__((ext_vector_type(8))) short bf16x8;
typedef __attribute__((ext_vector_type(16))) float f32x16;
typedef unsigned long long u64;
typedef unsigned int u32;
typedef unsigned short ushort_t;

// ---- bf16 split helpers (RNE) ----
__device__ __forceinline__ ushort_t f2bf(float x) {
    u32 u = __float_as_uint(x);
    u32 r = (u + 0x7FFFu + ((u >> 16) & 1u)) >> 16;
    return (ushort_t)r;
}
__device__ __forceinline__ float bf2f(ushort_t h) {
    return __uint_as_float(((u32)h) << 16);
}

// ---------------- init: z_rest = z_enc, z_dec = 0 ----------------
__global__ void init_kernel(const float* __restrict__ ze,
                            float* __restrict__ zrest,
                            float* __restrict__ zdec) {
    int i = blockIdx.x * 256 + threadIdx.x;
    zrest[i] = ze[i];
    zdec[i]  = 0.0f;
}

// ---------------- e_sq[v] = sum_c emb[v][c]^2 ----------------
__global__ void esq_kernel(const float* __restrict__ emb,
                           float* __restrict__ esq) {
    int v    = blockIdx.x * 4 + (threadIdx.x >> 6);
    int lane = threadIdx.x & 63;
    float2 e = *(const float2*)(emb + (size_t)v * CDIM + lane * 2);
    float s = e.x * e.x + e.y * e.y;
    #pragma unroll
    for (int d = 32; d; d >>= 1) s += __shfl_xor(s, d, 64);
    if (lane == 0) esq[v] = s;
}

// ---------------- emb -> bf16 hi/lo split ----------------
__global__ void emb_split_kernel(const float* __restrict__ emb,
                                 ushort_t* __restrict__ eh,
                                 ushort_t* __restrict__ el) {
    int i = blockIdx.x * 256 + threadIdx.x;
    float x = emb[i];
    ushort_t h = f2bf(x);
    eh[i] = h;
    el[i] = f2bf(x - bf2f(h));
}

// ---------------- area downsample -> bf16 hi/lo rows ----------------
__global__ void down_kernel(const float* __restrict__ zr,
                            ushort_t* __restrict__ zh,
                            ushort_t* __restrict__ zl,
                            int pn, int f) {
    int idx = blockIdx.x * 256 + threadIdx.x;
    int row = idx >> 7;
    int c   = idx & 127;
    int pp  = pn * pn;
    int b   = row / pp;
    int rem = row - b * pp;
    int ph  = rem / pn;
    int pw  = rem - ph * pn;
    const float* src = zr + (((size_t)b * CDIM + c) * HDIM + ph * f) * WDIM + pw * f;
    float s = 0.0f;
    if (f >= 4) {
        for (int u = 0; u < f; u++) {
            const float4* s4 = (const float4*)(src + u * WDIM);
            for (int v = 0; v < f / 4; v++) {
                float4 a = s4[v];
                s += a.x + a.y + a.z + a.w;
            }
        }
    } else {
        for (int u = 0; u < f; u++)
            for (int v = 0; v < f; v++)
                s += src[u * WDIM + v];
    }
    float m = s * (1.0f / (f * f));
    ushort_t h = f2bf(m);
    zh[(size_t)row * CDIM + c] = h;
    zl[(size_t)row * CDIM + c] = f2bf(m - bf2f(h));
}

// ---------------- MFMA argmin ----------------
// Block = 4 waves; wave w owns rows [tile*128 + w*32, +32); waves share codes.
// Grid = tiles * slices; block's code range = [slice*cps, +cps).
// dot via split-bf16: xh*eh + xh*el + xl*eh (3 MFMA products, K=128 in 8 chunks).
// Merge across slices with atomicMin on packed (score_bits, code) u64 keys.
__global__ __launch_bounds__(256) void argmin_mfma_kernel(
        const ushort_t* __restrict__ zd_hi, const ushort_t* __restrict__ zd_lo,
        const ushort_t* __restrict__ emb_hi, const ushort_t* __restrict__ emb_lo,
        const float* __restrict__ esq,
        u64* __restrict__ keys,
        int tiles, int cps) {
    int tile  = blockIdx.x % tiles;
    int slice = blockIdx.x / tiles;
    int code0 = slice * cps;
    int tid = threadIdx.x;
    int wv  = tid >> 6;
    int l   = tid & 63;
    int l31 = l & 31;
    int lh  = l >> 5;

    int arow = tile * 128 + wv * 32 + l31;
    const ushort_t* ah = zd_hi + (size_t)arow * CDIM + lh * 8;
    const ushort_t* al = zd_lo + (size_t)arow * CDIM + lh * 8;
    bf16x8 a_hi[8], a_lo[8];
    #pragma unroll
    for (int c = 0; c < 8; c++) {
        a_hi[c] = *(const bf16x8*)(ah + c * 16);
        a_lo[c] = *(const bf16x8*)(al + c * 16);
    }

    float best[16];
    int   bidx[16];
    #pragma unroll
    for (int r = 0; r < 16; r++) { best[r] = 1e38f; bidx[r] = 0; }

    for (int it = 0; it < cps; it += 32) {
        int code = code0 + it + l31;
        const ushort_t* bh = emb_hi + (size_t)code * CDIM + lh * 8;
        const ushort_t* bl = emb_lo + (size_t)code * CDIM + lh * 8;
        f32x16 acc0 = {0,0,0,0,0,0,0,0,0,0,0,0,0,0,0,0};
        f32x16 acc1 = {0,0,0,0,0,0,0,0,0,0,0,0,0,0,0,0};
        f32x16 acc2 = {0,0,0,0,0,0,0,0,0,0,0,0,0,0,0,0};
        #pragma unroll
        for (int c = 0; c < 8; c++) {
            bf16x8 vh = *(const bf16x8*)(bh + c * 16);
            bf16x8 vl = *(const bf16x8*)(bl + c * 16);
            acc0 = __builtin_amdgcn_mfma_f32_32x32x16_bf16(a_hi[c], vh, acc0, 0, 0, 0);
            acc1 = __builtin_amdgcn_mfma_f32_32x32x16_bf16(a_hi[c], vl, acc1, 0, 0, 0);
            acc2 = __builtin_amdgcn_mfma_f32_32x32x16_bf16(a_lo[c], vh, acc2, 0, 0, 0);
        }
        float es = esq[code];
        #pragma unroll
        for (int r = 0; r < 16; r++) {
            float dot = (acc0[r] + acc1[r]) + acc2[r];
            float s = fmaf(-2.0f, dot, es);
            if (s < best[r]) { best[r] = s; bidx[r] = code; }
        }
    }

    // reduce across the 32 lanes of each half (they share rows, differ in code)
    #pragma unroll
    for (int r = 0; r < 16; r++) {
        u32 fb = __float_as_uint(best[r]);
        fb = (fb & 0x80000000u) ? ~fb : (fb | 0x80000000u);
        u64 key = ((u64)fb << 32) | (u32)bidx[r];
        #pragma unroll
        for (int d = 1; d < 32; d <<= 1) {
            u64 o = __shfl_xor(key, d, 64);
            key = (o < key) ? o : key;
        }
        if (l31 == 0) {
            int rw = tile * 128 + wv * 32 + (r & 3) + 8 * (r >> 2) + 4 * lh;
            atomicMin(&keys[rw], key);
        }
    }
}

// ---------------- bicubic weight (a = -0.75), t = |arg| <= 2 ----------------
__device__ __forceinline__ float cubicw(float t) {
    float t2 = t * t;
    if (t <= 1.0f) return (1.25f * t - 2.25f) * t2 + 1.0f;
    return -0.75f * (((t - 5.0f) * t + 8.0f) * t - 4.0f);
}

// ---------------- upsample + residual update + output ----------------
__global__ __launch_bounds__(256) void up_kernel(
        const float* __restrict__ emb,
        const u64* __restrict__ keys,
        float* __restrict__ zdec,
        float* __restrict__ zrest,
        float* __restrict__ out,
        int pn, int last) {
    __shared__ float wtab[32][5];
    __shared__ int   itab[32][5];
    int tid = threadIdx.x;
    if (!last && tid < 128) {
        int pos = tid >> 2, tap = tid & 3;
        float s  = (float)pn * (1.0f / 32.0f);
        float x  = ((float)pos + 0.5f) * s - 0.5f;
        float x0 = floorf(x);
        float t  = x - x0;
        int   off = tap - 1;
        float w  = cubicw(fabsf((float)off - t));
        int   jj = (int)x0 + off;
        jj = min(max(jj, 0), pn - 1);
        wtab[pos][tap] = w;
        itab[pos][tap] = jj;
    }
    __syncthreads();

    int i  = blockIdx.x * 256 + tid;
    int w_ = i & 31;
    int h  = (i >> 5) & 31;
    int c  = (i >> 10) & 127;
    int b  = i >> 17;

    float zu;
    if (last) {
        int tok = (int)(keys[(b << 10) + (h << 5) + w_] & 0xFFFFFFFFull);
        zu = emb[(size_t)tok * CDIM + c];
    } else {
        int base = b * pn * pn;
        zu = 0.0f;
        #pragma unroll
        for (int u = 0; u < 4; u++) {
            float whu = wtab[h][u];
            int   ih  = itab[h][u] * pn;
            float acc = 0.0f;
            #pragma unroll
            for (int v = 0; v < 4; v++) {
                int tok = (int)(keys[base + ih + itab[w_][v]] & 0xFFFFFFFFull);
                acc += wtab[w_][v] * emb[(size_t)tok * CDIM + c];
            }
            zu += whu * acc;
        }
    }
    float nd = zdec[i] + zu;
    zdec[i]  = nd;
    zrest[i] = zrest[i] - zu;
    out[i]   = nd;
}

extern "C" void kernel_launch(void* const* d_in, const int* in_sizes, int n_in,
                              void* d_out, int out_size, void* d_ws, size_t ws_size,
                              hipStream_t stream) {
    const float* z_enc = (const float*)d_in[0];
    const float* emb   = (const float*)d_in[1];
    float* out = (float*)d_out;
    float* ws  = (float*)d_ws;

    // ws layout (float offsets)
    float*    zrest  = ws;                                   // 2M
    float*    zdec   = ws + (size_t)NTOT;                    // 2M
    ushort_t* zd_hi  = (ushort_t*)(ws + 2 * (size_t)NTOT);   // 16384*128 u16 = 1M floats
    ushort_t* zd_lo  = (ushort_t*)(ws + 2 * (size_t)NTOT + 1048576);
    ushort_t* emb_hi = (ushort_t*)(ws + 2 * (size_t)NTOT + 2097152);  // 512K floats
    ushort_t* emb_lo = (ushort_t*)(ws + 2 * (size_t)NTOT + 2621440);
    float*    esq    = ws + 2 * (size_t)NTOT + 3145728;      // 8192 floats
    u64*      keys   = (u64*)(ws + 2 * (size_t)NTOT + 3153920); // 16384 u64

    init_kernel<<<NTOT / 256, 256, 0, stream>>>(z_enc, zrest, zdec);
    esq_kernel<<<NCODES / 4, 256, 0, stream>>>(emb, esq);
    emb_split_kernel<<<NCODES * CDIM / 256, 256, 0, stream>>>(emb, emb_hi, emb_lo);

    const int MS_[6]     = {1, 2, 4, 8, 16, 32};
    const int SLICES_[6] = {128, 128, 128, 32, 16, 4};
    for (int lvl = 0; lvl < 6; lvl++) {
        int pn    = MS_[lvl];
        int last  = (lvl == 5) ? 1 : 0;
        int rows  = BATCH * pn * pn;
        int tiles = (rows + 127) / 128;
        int slices = SLICES_[lvl];
        int cps   = NCODES / slices;

        down_kernel<<<rows * CDIM / 256, 256, 0, stream>>>(zrest, zd_hi, zd_lo,
                                                           pn, HDIM / pn);
        hipMemsetAsync(keys, 0xFF, (size_t)tiles * 128 * sizeof(u64), stream);
        argmin_mfma_kernel<<<tiles * slices, 256, 0, stream>>>(
            zd_hi, zd_lo, emb_hi, emb_lo, esq, keys, tiles, cps);
        up_kernel<<<NTOT / 256, 256, 0, stream>>>(emb, keys, zdec, zrest,
                                                  out + (size_t)lvl * NTOT, pn, last);
    }
}

// Round 3
// 577.966 us; speedup vs baseline: 4.8802x; 1.2334x over previous
//
#include <hip/hip_runtime.h>
#include <hip/hip_bf16.h>

#define NCODES 8192
#define CDIM 128
#define NTOT (16*128*32*32)   // 2097152

typedef __attribute__((ext_vector_type(8))) short bf16x8;
typedef __attribute__((ext_vector_type(16))) float f32x16;
typedef unsigned long long u64;
typedef unsigned int u32;
typedef unsigned short ushort_t;

__device__ __forceinline__ ushort_t f2bf(float x) {
    u32 u = __float_as_uint(x);
    u32 r = (u + 0x7FFFu + ((u >> 16) & 1u)) >> 16;
    return (ushort_t)r;
}
__device__ __forceinline__ float bf2f(ushort_t h) {
    return __uint_as_float(((u32)h) << 16);
}

// ---------------- e_sq[v] = sum_c emb[v][c]^2 ----------------
__global__ void esq_kernel(const float* __restrict__ emb,
                           float* __restrict__ esq) {
    int v    = blockIdx.x * 4 + (threadIdx.x >> 6);
    int lane = threadIdx.x & 63;
    float2 e = *(const float2*)(emb + (size_t)v * CDIM + lane * 2);
    float s = e.x * e.x + e.y * e.y;
    #pragma unroll
    for (int d = 32; d; d >>= 1) s += __shfl_xor(s, d, 64);
    if (lane == 0) esq[v] = s;
}

// ---------------- pack f32 [nrows][128] -> MFMA fragment layout ----------------
// Fragment (rb, c, s): 64 lanes x 8 bf16, element: src[rb*32 + (l&31)][c*16 + (l>>5)*8 + e]
// dst offset (ushort): ((rb*8 + c)*2 + s)*512 + l*8.  scale applied before split.
__global__ __launch_bounds__(256) void pack_kernel(const float* __restrict__ src,
        ushort_t* __restrict__ dst, int nrows, float scale) {
    __shared__ float sm[32][129];
    int rb = blockIdx.x, t = threadIdx.x;
    int rl = t >> 3, d0 = (t & 7) * 16;
    int row = rb * 32 + rl;
    if (row > nrows - 1) row = nrows - 1;
    const float4* s4 = (const float4*)(src + (size_t)row * CDIM + d0);
    #pragma unroll
    for (int j = 0; j < 4; j++) {
        float4 v = s4[j];
        sm[rl][d0 + 4*j + 0] = v.x; sm[rl][d0 + 4*j + 1] = v.y;
        sm[rl][d0 + 4*j + 2] = v.z; sm[rl][d0 + 4*j + 3] = v.w;
    }
    __syncthreads();
    #pragma unroll
    for (int k = 0; k < 2; k++) {
        int s = t + 256 * k;
        int c = s >> 6, l = s & 63;
        int r = l & 31, dbase = c * 16 + (l >> 5) * 8;
        bf16x8 vh, vl;
        #pragma unroll
        for (int e = 0; e < 8; e++) {
            float x = sm[r][dbase + e] * scale;
            ushort_t hh = f2bf(x);
            vh[e] = (short)hh;
            vl[e] = (short)f2bf(x - bf2f(hh));
        }
        size_t base = ((size_t)(rb * 8 + c) * 2) * 512 + (size_t)l * 8;
        *(bf16x8*)(dst + base)       = vh;
        *(bf16x8*)(dst + base + 512) = vl;
    }
}

// ---------------- L5 pack: rows=(b,h,w) straight from [B][C][H][W], scale=-2 ----------------
__global__ __launch_bounds__(256) void pack_l5_kernel(const float* __restrict__ src,
        ushort_t* __restrict__ dst) {
    __shared__ float sm[128][36];
    int bh = blockIdx.x;            // rb == bh
    int b = bh >> 5, h = bh & 31;
    int t = threadIdx.x;
    int d = t >> 1, w0 = (t & 1) * 16;
    const float* sp = src + (((size_t)b * CDIM + d) * 32 + h) * 32 + w0;
    #pragma unroll
    for (int j = 0; j < 16; j++) sm[d][w0 + j] = sp[j];
    __syncthreads();
    #pragma unroll
    for (int k = 0; k < 2; k++) {
        int s = t + 256 * k;
        int c = s >> 6, l = s & 63;
        int w = l & 31, dbase = c * 16 + (l >> 5) * 8;
        bf16x8 vh, vl;
        #pragma unroll
        for (int e = 0; e < 8; e++) {
            float x = sm[dbase + e][w] * -2.0f;
            ushort_t hh = f2bf(x);
            vh[e] = (short)hh;
            vl[e] = (short)f2bf(x - bf2f(hh));
        }
        size_t base = ((size_t)(bh * 8 + c) * 2) * 512 + (size_t)l * 8;
        *(bf16x8*)(dst + base)       = vh;
        *(bf16x8*)(dst + base + 512) = vl;
    }
}

// ---------------- wave-parallel area downsample -> zd_f32[row][dim] ----------------
__global__ __launch_bounds__(256) void down_kernel(const float* __restrict__ src,
        float* __restrict__ zd, int lf /*log2 f*/) {
    int f  = 1 << lf;
    int ff = f * f;
    int llpi = (2 * lf > 6) ? 6 : 2 * lf;
    int lpi  = 1 << llpi;
    int epl  = ff >> llpi;
    int t    = blockIdx.x * 256 + threadIdx.x;
    int item = t >> llpi;
    int wi   = t & (lpi - 1);
    int row = item >> 7, dim = item & 127;
    int lpn = 5 - lf;
    int b  = row >> (2 * lpn);
    int rem = row & ((1 << (2 * lpn)) - 1);
    int ph = rem >> lpn, pw = rem & ((1 << lpn) - 1);
    const float* sp = src + (((size_t)b * CDIM + dim) * 32 + (ph << lf)) * 32 + (pw << lf);
    float s = 0.f;
    for (int k = 0; k < epl; k++) {
        int flat = wi * epl + k;
        int u = flat >> lf, v = flat & (f - 1);
        s += sp[u * 32 + v];
    }
    for (int d = lpi >> 1; d; d >>= 1) s += __shfl_xor(s, d, 64);
    if (wi == 0) zd[(size_t)row * CDIM + dim] = s * (1.0f / (float)ff);
}

// ---------------- MFMA argmin over packed fragments ----------------
__global__ __launch_bounds__(256) void argmin_kernel(
        const ushort_t* __restrict__ apk, const ushort_t* __restrict__ bpk,
        const float* __restrict__ esq, u64* __restrict__ keys,
        int tiles, int cps) {
    int tile  = blockIdx.x % tiles;
    int slice = blockIdx.x / tiles;
    int code0 = slice * cps;
    int tid = threadIdx.x, wv = tid >> 6, l = tid & 63, l31 = l & 31, lh = l >> 5;

    int rb = tile * 4 + wv;
    const ushort_t* ap = apk + (size_t)rb * 16 * 512 + l * 8;
    bf16x8 a_hi[8], a_lo[8];
    #pragma unroll
    for (int c = 0; c < 8; c++) {
        a_hi[c] = *(const bf16x8*)(ap + (2 * c) * 512);
        a_lo[c] = *(const bf16x8*)(ap + (2 * c + 1) * 512);
    }

    float best[16];
    int   bidx[16];
    #pragma unroll
    for (int r = 0; r < 16; r++) { best[r] = 1e38f; bidx[r] = 0; }

    const ushort_t* bp0 = bpk + (size_t)(code0 >> 5) * 16 * 512 + l * 8;
    for (int it = 0; it < cps; it += 32) {
        const ushort_t* bp = bp0 + (size_t)(it >> 5) * 16 * 512;
        f32x16 acc0 = {0,0,0,0,0,0,0,0,0,0,0,0,0,0,0,0};
        f32x16 acc1 = {0,0,0,0,0,0,0,0,0,0,0,0,0,0,0,0};
        f32x16 acc2 = {0,0,0,0,0,0,0,0,0,0,0,0,0,0,0,0};
        #pragma unroll
        for (int c = 0; c < 8; c++) {
            bf16x8 vh = *(const bf16x8*)(bp + (2 * c) * 512);
            bf16x8 vl = *(const bf16x8*)(bp + (2 * c + 1) * 512);
            acc0 = __builtin_amdgcn_mfma_f32_32x32x16_bf16(a_hi[c], vh, acc0, 0, 0, 0);
            acc1 = __builtin_amdgcn_mfma_f32_32x32x16_bf16(a_hi[c], vl, acc1, 0, 0, 0);
            acc2 = __builtin_amdgcn_mfma_f32_32x32x16_bf16(a_lo[c], vh, acc2, 0, 0, 0);
        }
        int code = code0 + it + l31;
        float es = esq[code];
        #pragma unroll
        for (int r = 0; r < 16; r++) {
            float s = es + ((acc0[r] + acc1[r]) + acc2[r]);
            bool lt = s < best[r];
            best[r] = lt ? s : best[r];
            bidx[r] = lt ? code : bidx[r];
        }
    }

    #pragma unroll
    for (int r = 0; r < 16; r++) {
        u32 fb = __float_as_uint(best[r]);
        fb = (fb & 0x80000000u) ? ~fb : (fb | 0x80000000u);
        u64 key = ((u64)fb << 32) | (u32)bidx[r];
        #pragma unroll
        for (int d = 1; d < 32; d <<= 1) {
            u64 o = __shfl_xor(key, d, 64);
            key = (o < key) ? o : key;
        }
        if (l31 == 0) {
            int rw = tile * 128 + wv * 32 + (r & 3) + 8 * (r >> 2) + 4 * lh;
            atomicMin(&keys[rw], key);
        }
    }
}

// ---------------- bicubic weight (a = -0.75) ----------------
__device__ __forceinline__ float cubicw(float t) {
    float t2 = t * t;
    if (t <= 1.0f) return (1.25f * t - 2.25f) * t2 + 1.0f;
    return -0.75f * (((t - 5.0f) * t + 8.0f) * t - 4.0f);
}

// ---------------- upsample + residual update + output (float4 over w) ----------------
__global__ __launch_bounds__(256) void up_kernel(
        const float* __restrict__ emb,
        const u64* __restrict__ keys,
        const float* __restrict__ src,   // z_enc (lvl0) or zrest
        const float* __restrict__ prev,  // out[lvl-1] (unused if first)
        float* __restrict__ zrest,
        float* __restrict__ out,
        int pn, int last, int first) {
    __shared__ float wtab[32][4];
    __shared__ int   itab[32][4];
    int tid = threadIdx.x;
    if (!last && tid < 128) {
        int pos = tid >> 2, tap = tid & 3;
        float s  = (float)pn * (1.0f / 32.0f);
        float x  = ((float)pos + 0.5f) * s - 0.5f;
        float x0 = floorf(x);
        float t  = x - x0;
        int   off = tap - 1;
        float w  = cubicw(fabsf((float)off - t));
        int   jj = (int)x0 + off;
        jj = min(max(jj, 0), pn - 1);
        wtab[pos][tap] = w;
        itab[pos][tap] = jj;
    }
    __syncthreads();

    int t  = blockIdx.x * 256 + tid;
    int w4 = (t & 7) << 2;
    int h  = (t >> 3) & 31;
    int c  = (t >> 8) & 127;
    int b  = t >> 15;
    size_t i = (((size_t)b * CDIM + c) * 32 + h) * 32 + w4;

    float zu[4];
    if (last) {
        int kb = (b << 10) + (h << 5) + w4;
        #pragma unroll
        for (int j = 0; j < 4; j++) {
            int tok = (int)(keys[kb + j] & 0xFFFFFFFFull);
            zu[j] = emb[(size_t)tok * CDIM + c];
        }
    } else {
        int base = b * pn * pn;
        #pragma unroll
        for (int j = 0; j < 4; j++) zu[j] = 0.f;
        #pragma unroll
        for (int u = 0; u < 4; u++) {
            float whu = wtab[h][u];
            int   ih  = itab[h][u] * pn;
            #pragma unroll
            for (int j = 0; j < 4; j++) {
                float acc = 0.f;
                #pragma unroll
                for (int v = 0; v < 4; v++) {
                    int tok = (int)(keys[base + ih + itab[w4 + j][v]] & 0xFFFFFFFFull);
                    acc += wtab[w4 + j][v] * emb[(size_t)tok * CDIM + c];
                }
                zu[j] += whu * acc;
            }
        }
    }
    float4 sv = *(const float4*)(src + i);
    float4 pv = {0.f, 0.f, 0.f, 0.f};
    if (!first) pv = *(const float4*)(prev + i);
    float4 ov, rv;
    ov.x = pv.x + zu[0]; ov.y = pv.y + zu[1]; ov.z = pv.z + zu[2]; ov.w = pv.w + zu[3];
    rv.x = sv.x - zu[0]; rv.y = sv.y - zu[1]; rv.z = sv.z - zu[2]; rv.w = sv.w - zu[3];
    *(float4*)(out + i)   = ov;
    *(float4*)(zrest + i) = rv;
}

extern "C" void kernel_launch(void* const* d_in, const int* in_sizes, int n_in,
                              void* d_out, int out_size, void* d_ws, size_t ws_size,
                              hipStream_t stream) {
    const float* z_enc = (const float*)d_in[0];
    const float* emb   = (const float*)d_in[1];
    float* out = (float*)d_out;
    float* ws  = (float*)d_ws;

    // ws layout (float offsets)
    float*    zrest  = ws;                                // 2,097,152
    float*    zd_f32 = ws + 2097152;                      // 2,097,152
    ushort_t* zd_pk  = (ushort_t*)(ws + 4194304);         // 4,194,304 ushort
    ushort_t* emb_pk = (ushort_t*)(ws + 6291456);         // 2,097,152 ushort
    float*    esq    = ws + 7340032;                      // 8192
    u64*      keys   = (u64*)(ws + 7348224);              // 16384 u64

    esq_kernel<<<NCODES / 4, 256, 0, stream>>>(emb, esq);
    pack_kernel<<<NCODES / 32, 256, 0, stream>>>(emb, emb_pk, NCODES, 1.0f);

    const int MS_[6] = {1, 2, 4, 8, 16, 32};
    const int SL_[6] = {128, 128, 128, 64, 32, 16};
    for (int lvl = 0; lvl < 6; lvl++) {
        int pn     = MS_[lvl];
        int lf     = 5 - lvl;               // log2(32/pn)
        int rows   = 16 * pn * pn;
        int tiles  = (rows + 127) / 128;
        int slices = SL_[lvl];
        int cps    = NCODES / slices;
        const float* src = lvl ? zrest : z_enc;

        if (lvl < 5) {
            int ff  = 1 << (2 * lf);
            int lpi = ff < 64 ? ff : 64;
            down_kernel<<<rows * 128 * lpi / 256, 256, 0, stream>>>(src, zd_f32, lf);
            pack_kernel<<<tiles * 4, 256, 0, stream>>>(zd_f32, zd_pk, rows, -2.0f);
        } else {
            pack_l5_kernel<<<512, 256, 0, stream>>>(src, zd_pk);
        }
        hipMemsetAsync(keys, 0xFF, (size_t)tiles * 128 * sizeof(u64), stream);
        argmin_kernel<<<tiles * slices, 256, 0, stream>>>(
            zd_pk, emb_pk, esq, keys, tiles, cps);
        up_kernel<<<NTOT / 4 / 256, 256, 0, stream>>>(
            emb, keys, src, lvl ? (out + (size_t)(lvl - 1) * NTOT) : out,
            zrest, out + (size_t)lvl * NTOT, pn, lvl == 5 ? 1 : 0, lvl == 0 ? 1 : 0);
    }
}

// Round 4
// 517.396 us; speedup vs baseline: 5.4515x; 1.1171x over previous
//
#include <hip/hip_runtime.h>
#include <hip/hip_bf16.h>

#define NCODES 8192
#define CDIM 128
#define NTOT (16*128*32*32)   // 2097152

typedef __attribute__((ext_vector_type(8))) short bf16x8;
typedef __attribute__((ext_vector_type(16))) float f32x16;
typedef unsigned long long u64;
typedef unsigned int u32;
typedef unsigned short ushort_t;

__device__ __forceinline__ ushort_t f2bf(float x) {
    u32 u = __float_as_uint(x);
    u32 r = (u + 0x7FFFu + ((u >> 16) & 1u)) >> 16;
    return (ushort_t)r;
}
__device__ __forceinline__ float bf2f(ushort_t h) {
    return __uint_as_float(((u32)h) << 16);
}

__device__ __forceinline__ void gload_lds16(const void* g, void* l) {
    __builtin_amdgcn_global_load_lds(
        (const __attribute__((address_space(1))) unsigned int*)g,
        (__attribute__((address_space(3))) unsigned int*)l, 16, 0, 0);
}

// ---------------- e_sq[v] = sum_c emb[v][c]^2 ----------------
__global__ void esq_kernel(const float* __restrict__ emb,
                           float* __restrict__ esq) {
    int v    = blockIdx.x * 4 + (threadIdx.x >> 6);
    int lane = threadIdx.x & 63;
    float2 e = *(const float2*)(emb + (size_t)v * CDIM + lane * 2);
    float s = e.x * e.x + e.y * e.y;
    #pragma unroll
    for (int d = 32; d; d >>= 1) s += __shfl_xor(s, d, 64);
    if (lane == 0) esq[v] = s;
}

// ---------------- pack f32 [nrows][128] -> MFMA fragment layout ----------------
// Fragment (rb, c, s): 64 lanes x 8 bf16, element: src[rb*32 + (l&31)][c*16 + (l>>5)*8 + e]
// dst offset (ushort): ((rb*8 + c)*2 + s)*512 + l*8.  scale applied before split.
__global__ __launch_bounds__(256) void pack_kernel(const float* __restrict__ src,
        ushort_t* __restrict__ dst, int nrows, float scale) {
    __shared__ float sm[32][129];
    int rb = blockIdx.x, t = threadIdx.x;
    int rl = t >> 3, d0 = (t & 7) * 16;
    int row = rb * 32 + rl;
    if (row > nrows - 1) row = nrows - 1;
    const float4* s4 = (const float4*)(src + (size_t)row * CDIM + d0);
    #pragma unroll
    for (int j = 0; j < 4; j++) {
        float4 v = s4[j];
        sm[rl][d0 + 4*j + 0] = v.x; sm[rl][d0 + 4*j + 1] = v.y;
        sm[rl][d0 + 4*j + 2] = v.z; sm[rl][d0 + 4*j + 3] = v.w;
    }
    __syncthreads();
    #pragma unroll
    for (int k = 0; k < 2; k++) {
        int s = t + 256 * k;
        int c = s >> 6, l = s & 63;
        int r = l & 31, dbase = c * 16 + (l >> 5) * 8;
        bf16x8 vh, vl;
        #pragma unroll
        for (int e = 0; e < 8; e++) {
            float x = sm[r][dbase + e] * scale;
            ushort_t hh = f2bf(x);
            vh[e] = (short)hh;
            vl[e] = (short)f2bf(x - bf2f(hh));
        }
        size_t base = ((size_t)(rb * 8 + c) * 2) * 512 + (size_t)l * 8;
        *(bf16x8*)(dst + base)       = vh;
        *(bf16x8*)(dst + base + 512) = vl;
    }
}

// ---------------- L5 pack: rows=(b,h,w) straight from [B][C][H][W], scale=-2 ----------------
__global__ __launch_bounds__(256) void pack_l5_kernel(const float* __restrict__ src,
        ushort_t* __restrict__ dst) {
    __shared__ float sm[128][36];
    int bh = blockIdx.x;            // rb == bh
    int b = bh >> 5, h = bh & 31;
    int t = threadIdx.x;
    int d = t >> 1, w0 = (t & 1) * 16;
    const float* sp = src + (((size_t)b * CDIM + d) * 32 + h) * 32 + w0;
    #pragma unroll
    for (int j = 0; j < 16; j++) sm[d][w0 + j] = sp[j];
    __syncthreads();
    #pragma unroll
    for (int k = 0; k < 2; k++) {
        int s = t + 256 * k;
        int c = s >> 6, l = s & 63;
        int w = l & 31, dbase = c * 16 + (l >> 5) * 8;
        bf16x8 vh, vl;
        #pragma unroll
        for (int e = 0; e < 8; e++) {
            float x = sm[dbase + e][w] * -2.0f;
            ushort_t hh = f2bf(x);
            vh[e] = (short)hh;
            vl[e] = (short)f2bf(x - bf2f(hh));
        }
        size_t base = ((size_t)(bh * 8 + c) * 2) * 512 + (size_t)l * 8;
        *(bf16x8*)(dst + base)       = vh;
        *(bf16x8*)(dst + base + 512) = vl;
    }
}

// ---------------- wave-parallel area downsample -> zd_f32[row][dim] ----------------
__global__ __launch_bounds__(256) void down_kernel(const float* __restrict__ src,
        float* __restrict__ zd, int lf /*log2 f*/) {
    int f  = 1 << lf;
    int ff = f * f;
    int llpi = (2 * lf > 6) ? 6 : 2 * lf;
    int lpi  = 1 << llpi;
    int epl  = ff >> llpi;
    int t    = blockIdx.x * 256 + threadIdx.x;
    int item = t >> llpi;
    int wi   = t & (lpi - 1);
    int row = item >> 7, dim = item & 127;
    int lpn = 5 - lf;
    int b  = row >> (2 * lpn);
    int rem = row & ((1 << (2 * lpn)) - 1);
    int ph = rem >> lpn, pw = rem & ((1 << lpn) - 1);
    const float* sp = src + (((size_t)b * CDIM + dim) * 32 + (ph << lf)) * 32 + (pw << lf);
    float s = 0.f;
    for (int k = 0; k < epl; k++) {
        int flat = wi * epl + k;
        int u = flat >> lf, v = flat & (f - 1);
        s += sp[u * 32 + v];
    }
    for (int d = lpi >> 1; d; d >>= 1) s += __shfl_xor(s, d, 64);
    if (wi == 0) zd[(size_t)row * CDIM + dim] = s * (1.0f / (float)ff);
}

// ---------------- MFMA argmin: 8 waves / 256 rows per block, B in LDS ----------------
// LDS double buffer: 2 x 16 KB. Per 32-code step: stage 16 fragments (16 KB)
// cooperatively (2 global_load_lds x 8 waves), compute 24 chained MFMAs/wave.
__global__ __launch_bounds__(512) void argmin_kernel(
        const ushort_t* __restrict__ apk, const ushort_t* __restrict__ bpk,
        const float* __restrict__ esq, u64* __restrict__ keys,
        int tiles, int cps) {
    __shared__ ushort_t lds[2][8192];   // 2 x 16 KB

    int tile  = blockIdx.x % tiles;
    int slice = blockIdx.x / tiles;
    int code0 = slice * cps;
    int steps = cps >> 5;
    int tid = threadIdx.x, wv = tid >> 6, l = tid & 63, l31 = l & 31, lh = l >> 5;

    // A fragments: this wave's 32 rows (row-block rb), 8 k-chunks, hi/lo
    int rb = tile * 8 + wv;
    const ushort_t* ap = apk + (size_t)rb * 16 * 512 + l * 8;
    bf16x8 a_hi[8], a_lo[8];
    #pragma unroll
    for (int c = 0; c < 8; c++) {
        a_hi[c] = *(const bf16x8*)(ap + (2 * c) * 512);
        a_lo[c] = *(const bf16x8*)(ap + (2 * c + 1) * 512);
    }

    float best[16];
    int   bidx[16];
    #pragma unroll
    for (int r = 0; r < 16; r++) { best[r] = 1e38f; bidx[r] = 0; }

    // B slice base (bytes): one 32-code block = 16 fragments = 16384 B contiguous
    const char* bbase = (const char*)bpk + (size_t)(code0 >> 5) * 16384;
    int issue = wv * 2;                        // this wave's 2 staging chunks
    ushort_t* l0 = &lds[0][issue * 512];
    ushort_t* l1 = &lds[1][issue * 512];

    // prologue: stage step 0 into buf 0
    {
        const char* g = bbase + (size_t)issue * 1024 + (size_t)l * 16;
        gload_lds16(g, l0);
        gload_lds16(g + 1024, l0 + 512);
    }

    int cur = 0;
    for (int it = 0; it < steps; ++it) {
        __syncthreads();   // implicit vmcnt(0)+lgkmcnt(0): staged buf[cur] ready
        if (it + 1 < steps) {
            const char* g = bbase + (size_t)(it + 1) * 16384
                          + (size_t)issue * 1024 + (size_t)l * 16;
            ushort_t* ld = cur ? l0 : l1;
            gload_lds16(g, ld);
            gload_lds16(g + 1024, ld + 512);
        }
        const ushort_t* lp = &lds[cur][0] + l * 8;
        f32x16 accA = {0,0,0,0,0,0,0,0,0,0,0,0,0,0,0,0};
        f32x16 accB = {0,0,0,0,0,0,0,0,0,0,0,0,0,0,0,0};
        #pragma unroll
        for (int c = 0; c < 8; c++) {
            bf16x8 vh = *(const bf16x8*)(lp + (2 * c) * 512);
            bf16x8 vl = *(const bf16x8*)(lp + (2 * c + 1) * 512);
            if (c & 1) {
                accB = __builtin_amdgcn_mfma_f32_32x32x16_bf16(a_hi[c], vh, accB, 0, 0, 0);
                accB = __builtin_amdgcn_mfma_f32_32x32x16_bf16(a_hi[c], vl, accB, 0, 0, 0);
                accB = __builtin_amdgcn_mfma_f32_32x32x16_bf16(a_lo[c], vh, accB, 0, 0, 0);
            } else {
                accA = __builtin_amdgcn_mfma_f32_32x32x16_bf16(a_hi[c], vh, accA, 0, 0, 0);
                accA = __builtin_amdgcn_mfma_f32_32x32x16_bf16(a_hi[c], vl, accA, 0, 0, 0);
                accA = __builtin_amdgcn_mfma_f32_32x32x16_bf16(a_lo[c], vh, accA, 0, 0, 0);
            }
        }
        int code = code0 + (it << 5) + l31;
        float es = esq[code];
        #pragma unroll
        for (int r = 0; r < 16; r++) {
            float s = es + (accA[r] + accB[r]);
            bool lt = s < best[r];
            best[r] = lt ? s : best[r];
            bidx[r] = lt ? code : bidx[r];
        }
        cur ^= 1;
    }

    #pragma unroll
    for (int r = 0; r < 16; r++) {
        u32 fb = __float_as_uint(best[r]);
        fb = (fb & 0x80000000u) ? ~fb : (fb | 0x80000000u);
        u64 key = ((u64)fb << 32) | (u32)bidx[r];
        #pragma unroll
        for (int d = 1; d < 32; d <<= 1) {
            u64 o = __shfl_xor(key, d, 64);
            key = (o < key) ? o : key;
        }
        if (l31 == 0) {
            int rw = tile * 256 + wv * 32 + (r & 3) + 8 * (r >> 2) + 4 * lh;
            atomicMin(&keys[rw], key);
        }
    }
}

// ---------------- bicubic weight (a = -0.75) ----------------
__device__ __forceinline__ float cubicw(float t) {
    float t2 = t * t;
    if (t <= 1.0f) return (1.25f * t - 2.25f) * t2 + 1.0f;
    return -0.75f * (((t - 5.0f) * t + 8.0f) * t - 4.0f);
}

// ---------------- upsample + residual update + output (float4 over w) ----------------
__global__ __launch_bounds__(256) void up_kernel(
        const float* __restrict__ emb,
        const u64* __restrict__ keys,
        const float* __restrict__ src,   // z_enc (lvl0) or zrest
        const float* __restrict__ prev,  // out[lvl-1] (unused if first)
        float* __restrict__ zrest,
        float* __restrict__ out,
        int pn, int last, int first) {
    __shared__ float wtab[32][4];
    __shared__ int   itab[32][4];
    int tid = threadIdx.x;
    if (!last && tid < 128) {
        int pos = tid >> 2, tap = tid & 3;
        float s  = (float)pn * (1.0f / 32.0f);
        float x  = ((float)pos + 0.5f) * s - 0.5f;
        float x0 = floorf(x);
        float t  = x - x0;
        int   off = tap - 1;
        float w  = cubicw(fabsf((float)off - t));
        int   jj = (int)x0 + off;
        jj = min(max(jj, 0), pn - 1);
        wtab[pos][tap] = w;
        itab[pos][tap] = jj;
    }
    __syncthreads();

    int t  = blockIdx.x * 256 + tid;
    int w4 = (t & 7) << 2;
    int h  = (t >> 3) & 31;
    int c  = (t >> 8) & 127;
    int b  = t >> 15;
    size_t i = (((size_t)b * CDIM + c) * 32 + h) * 32 + w4;

    float zu[4];
    if (last) {
        int kb = (b << 10) + (h << 5) + w4;
        #pragma unroll
        for (int j = 0; j < 4; j++) {
            int tok = (int)(keys[kb + j] & 0xFFFFFFFFull);
            zu[j] = emb[(size_t)tok * CDIM + c];
        }
    } else {
        int base = b * pn * pn;
        #pragma unroll
        for (int j = 0; j < 4; j++) zu[j] = 0.f;
        #pragma unroll
        for (int u = 0; u < 4; u++) {
            float whu = wtab[h][u];
            int   ih  = itab[h][u] * pn;
            #pragma unroll
            for (int j = 0; j < 4; j++) {
                float acc = 0.f;
                #pragma unroll
                for (int v = 0; v < 4; v++) {
                    int tok = (int)(keys[base + ih + itab[w4 + j][v]] & 0xFFFFFFFFull);
                    acc += wtab[w4 + j][v] * emb[(size_t)tok * CDIM + c];
                }
                zu[j] += whu * acc;
            }
        }
    }
    float4 sv = *(const float4*)(src + i);
    float4 pv = {0.f, 0.f, 0.f, 0.f};
    if (!first) pv = *(const float4*)(prev + i);
    float4 ov, rv;
    ov.x = pv.x + zu[0]; ov.y = pv.y + zu[1]; ov.z = pv.z + zu[2]; ov.w = pv.w + zu[3];
    rv.x = sv.x - zu[0]; rv.y = sv.y - zu[1]; rv.z = sv.z - zu[2]; rv.w = sv.w - zu[3];
    *(float4*)(out + i)   = ov;
    *(float4*)(zrest + i) = rv;
}

extern "C" void kernel_launch(void* const* d_in, const int* in_sizes, int n_in,
                              void* d_out, int out_size, void* d_ws, size_t ws_size,
                              hipStream_t stream) {
    const float* z_enc = (const float*)d_in[0];
    const float* emb   = (const float*)d_in[1];
    float* out = (float*)d_out;
    float* ws  = (float*)d_ws;

    // ws layout (float offsets)
    float*    zrest  = ws;                                // 2,097,152
    float*    zd_f32 = ws + 2097152;                      // 2,097,152
    ushort_t* zd_pk  = (ushort_t*)(ws + 4194304);         // 4,194,304 ushort
    ushort_t* emb_pk = (ushort_t*)(ws + 6291456);         // 2,097,152 ushort
    float*    esq    = ws + 7340032;                      // 8192
    u64*      keys   = (u64*)(ws + 7348224);              // 16384 u64

    esq_kernel<<<NCODES / 4, 256, 0, stream>>>(emb, esq);
    pack_kernel<<<NCODES / 32, 256, 0, stream>>>(emb, emb_pk, NCODES, 1.0f);

    const int MS_[6] = {1, 2, 4, 8, 16, 32};
    const int SL_[6] = {256, 256, 256, 64, 16, 16};
    for (int lvl = 0; lvl < 6; lvl++) {
        int pn     = MS_[lvl];
        int lf     = 5 - lvl;               // log2(32/pn)
        int rows   = 16 * pn * pn;
        int tiles  = (rows + 255) / 256;
        int slices = SL_[lvl];
        int cps    = NCODES / slices;
        const float* src = lvl ? zrest : z_enc;

        if (lvl < 5) {
            int ff  = 1 << (2 * lf);
            int lpi = ff < 64 ? ff : 64;
            down_kernel<<<rows * 128 * lpi / 256, 256, 0, stream>>>(src, zd_f32, lf);
            pack_kernel<<<tiles * 8, 256, 0, stream>>>(zd_f32, zd_pk, rows, -2.0f);
        } else {
            pack_l5_kernel<<<512, 256, 0, stream>>>(src, zd_pk);
        }
        hipMemsetAsync(keys, 0xFF, (size_t)tiles * 256 * sizeof(u64), stream);
        argmin_kernel<<<tiles * slices, 512, 0, stream>>>(
            zd_pk, emb_pk, esq, keys, tiles, cps);
        up_kernel<<<NTOT / 4 / 256, 256, 0, stream>>>(
            emb, keys, src, lvl ? (out + (size_t)(lvl - 1) * NTOT) : out,
            zrest, out + (size_t)lvl * NTOT, pn, lvl == 5 ? 1 : 0, lvl == 0 ? 1 : 0);
    }
}